// Round 1
// baseline (422.761 us; speedup 1.0000x reference)
//
#include <hip/hip_runtime.h>
#include <hip/hip_bf16.h>
#include <stdint.h>

// ---------------------------------------------------------------------------
// wannModel: x0 = x@Ws^T + bs;  h_{l+1} = relu(h_l@W_l^T + b_l) + x0 (32x);
//            out = softmax(h@Wo^T + bo)  over 64 classes.
//
// Transposed-orientation MFMA chain (out^T = W * h^T): C/D layout (col=lane&15
// = batch) is lane-compatible with the next layer's B-operand layout. k-index
// mismatch absorbed by pre-permuting weights' k axis with
// pi(8q+j+32kt) = 4q+(j&3)+16*(j>>2)+32kt in a prep kernel. h stays in
// registers across all 32 layers.
//
// R6: 16KB half-layer chunk double-buffer, all-8 bias loads hoisted per
// layer, h ping-pong (hA/hB).
// R7: counters showed Occupancy 26.3% == exactly the (37.5%+12.5%)/2 profile
// of a 768-block wave at 3 blocks/CU followed by a 256-block TAIL at 1
// block/CU for ~half the wall time (grid 1024 = 4/CU but launch_bounds
// capped residency at 3). Fix: __launch_bounds__(256,4) -> 4 blocks/CU
// (4x32KB LDS = 128KB <= 160KB; VGPR 84 <= 128 cap), grid exactly
// co-resident, no tail. LDS-read pipe (weight streaming, ~85us floor)
// becomes the next wall.
// ---------------------------------------------------------------------------

typedef short bs8 __attribute__((ext_vector_type(8)));   // 8 x bf16 bits
typedef float f32x4 __attribute__((ext_vector_type(4)));

union Frag { bs8 v; uint32_t u[4]; };
union F4   { float4 f; f32x4 v; };

__device__ __forceinline__ uint32_t cvtpk(float lo, float hi) {
#if __has_builtin(__builtin_amdgcn_cvt_pk_bf16_f32)
  auto r = __builtin_amdgcn_cvt_pk_bf16_f32(lo, hi);   // dst.lo=cvt(lo)
  uint32_t u; __builtin_memcpy(&u, &r, 4);
  return u;
#else
  union { float f; uint32_t u; } a, b; a.f = lo; b.f = hi;
  uint32_t ra = a.u + 0x7fffu + ((a.u >> 16) & 1u);    // RNE, no NaN check
  uint32_t rb = b.u + 0x7fffu + ((b.u >> 16) & 1u);
  return (ra >> 16) | (rb & 0xffff0000u);
#endif
}

// ---------------------------------------------------------------------------
// Preprocess: bf16 weight fragments in d_ws. uint16 layout:
//   [0,16384)       W_start frags, NATURAL k order
//   [16384,540672)  32 chain layers, PI-permuted k
//   [540672,548864) W_out frags, PI-permuted k
// Element offset in region: ((nt*4+kt)*64 + lane)*8 + j.
// Half-layer chunk c of a layer = nt in [4c,4c+4) = 8192 contiguous elements.
// ---------------------------------------------------------------------------
__global__ void prep_frags(const float* __restrict__ w_start,
                           const float* __restrict__ masked_w,
                           const float* __restrict__ w_out,
                           uint16_t* __restrict__ dst) {
  int t = blockIdx.x * 256 + threadIdx.x;
  if (t >= 68608) return;
  int lane = t & 63, kt = (t >> 6) & 3, q = lane >> 4, m15 = lane & 15;
  float f[8];
  if (t < 2048) {                              // W_start (natural k)
    int nt = (t >> 8) & 7;
    const float* s = w_start + (nt * 16 + m15) * 128 + q * 8 + kt * 32;
    #pragma unroll
    for (int j = 0; j < 8; ++j) f[j] = s[j];
  } else if (t < 67584) {                      // chain (pi-permuted k)
    int t2 = t - 2048, l = t2 >> 11, nt = (t2 >> 8) & 7;
    const float* s = masked_w + ((l * 128) + nt * 16 + m15) * 128 + q * 4 + kt * 32;
    #pragma unroll
    for (int j = 0; j < 8; ++j) f[j] = s[(j & 3) + 16 * (j >> 2)];
  } else {                                     // W_out (pi-permuted k)
    int t3 = t - 67584, nt = (t3 >> 8) & 3;
    const float* s = w_out + (nt * 16 + m15) * 128 + q * 4 + kt * 32;
    #pragma unroll
    for (int j = 0; j < 8; ++j) f[j] = s[(j & 3) + 16 * (j >> 2)];
  }
  uint4 o;
  o.x = cvtpk(f[0], f[1]); o.y = cvtpk(f[2], f[3]);
  o.z = cvtpk(f[4], f[5]); o.w = cvtpk(f[6], f[7]);
  *reinterpret_cast<uint4*>(dst + t * 8) = o;
}

// ---------------------------------------------------------------------------
// Main kernel: 1024 blocks x 256 threads (4 waves; wave owns 32 batch cols
// = 2 m-tiles of 16). LDS 32KB: X|Y 16KB half-layer chunk double-buffer.
// Chunk stream: Wsc0, Wsc1, L0c0, L0c1, ..., L31c1; even chunks -> X,
// odd -> Y. Passes 0,1 of every layer read X; passes 2,3 read Y.
// 4 blocks/CU resident (grid == exactly one dispatch wave, no tail).
// ---------------------------------------------------------------------------
extern __shared__ uint16_t lds[];

__global__ void __launch_bounds__(256, 4)
wann_main(const float* __restrict__ x,
          const float* __restrict__ b_start,
          const float* __restrict__ layer_b,
          const float* __restrict__ b_out,
          const uint16_t* __restrict__ wfrag,
          float* __restrict__ out) {
  const int tid  = threadIdx.x;
  const int lane = tid & 63;
  const int wave = tid >> 6;
  const int q    = lane >> 4;
  const int mc   = lane & 15;
  const long batch0 = (long)blockIdx.x * 128 + wave * 32;
  const f32x4 zero4 = {0.f, 0.f, 0.f, 0.f};

  uint16_t* X = lds;
  uint16_t* Y = lds + 8192;

  // stage one 16KB chunk (4 x width-16 global_load_lds per wave)
  auto stage = [&](uint16_t* dstb, const uint16_t* srcb) {
    #pragma unroll
    for (int i = 0; i < 4; ++i) {
      __builtin_amdgcn_global_load_lds(
          (const __attribute__((address_space(1))) void*)(srcb + i * 2048 + wave * 512 + lane * 8),
          (__attribute__((address_space(3))) void*)(dstb + i * 2048 + wave * 512),
          16, 0, 0);
    }
  };

  stage(X, wfrag);                           // W_start chunk0

  // ---- load x fragments (natural k: B[k=8q+j+32kt][batch=mc]) ----
  Frag xf[2][4];
  #pragma unroll
  for (int mt = 0; mt < 2; ++mt) {
    const float* xrow = x + (batch0 + mt * 16 + mc) * 128 + q * 8;
    #pragma unroll
    for (int kt = 0; kt < 4; ++kt) {
      float4 a = *reinterpret_cast<const float4*>(xrow + kt * 32);
      float4 b = *reinterpret_cast<const float4*>(xrow + kt * 32 + 4);
      xf[mt][kt].u[0] = cvtpk(a.x, a.y);
      xf[mt][kt].u[1] = cvtpk(a.z, a.w);
      xf[mt][kt].u[2] = cvtpk(b.x, b.y);
      xf[mt][kt].u[3] = cvtpk(b.z, b.w);
    }
  }

  Frag x0f[2][4], hA[2][4], hB[2][4];

  // ---- start layer half: 2 passes from `buf`, input xf, bias-only epilogue
  auto start_half = [&](const uint16_t* buf, int p0, const F4* bb) {
    #pragma unroll
    for (int pp = 0; pp < 2; ++pp) {
      const int p = p0 + pp;
      f32x4 acc[2][2];
      #pragma unroll
      for (int kt = 0; kt < 4; ++kt)
        #pragma unroll
        for (int ntl = 0; ntl < 2; ++ntl) {
          const int ntloc = 2 * pp + ntl;           // nt within chunk
          Frag wf;
          wf.v = *reinterpret_cast<const bs8*>(buf + ((ntloc * 4 + kt) * 64 + lane) * 8);
          #pragma unroll
          for (int mt = 0; mt < 2; ++mt) {
            f32x4 c = (kt == 0) ? bb[2 * p + ntl].v : acc[ntl][mt];
            acc[ntl][mt] = __builtin_amdgcn_mfma_f32_16x16x32_bf16(wf.v, xf[mt][kt].v, c, 0, 0, 0);
          }
        }
      #pragma unroll
      for (int mt = 0; mt < 2; ++mt)
        #pragma unroll
        for (int ntl = 0; ntl < 2; ++ntl) {
          x0f[mt][p].u[2 * ntl + 0] = cvtpk(acc[ntl][mt][0], acc[ntl][mt][1]);
          x0f[mt][p].u[2 * ntl + 1] = cvtpk(acc[ntl][mt][2], acc[ntl][mt][3]);
        }
    }
  };

  // ---- chain layer half: 2 passes from `buf`; hout[.][p] = bf16(relu+x0) --
  auto chain_half = [&](const uint16_t* buf, int p0, const F4* bb,
                        Frag (&hin)[2][4], Frag (&hout)[2][4]) {
    #pragma unroll
    for (int pp = 0; pp < 2; ++pp) {
      const int p = p0 + pp;
      f32x4 acc[2][2];
      #pragma unroll
      for (int kt = 0; kt < 4; ++kt)
        #pragma unroll
        for (int ntl = 0; ntl < 2; ++ntl) {
          const int ntloc = 2 * pp + ntl;
          Frag wf;
          wf.v = *reinterpret_cast<const bs8*>(buf + ((ntloc * 4 + kt) * 64 + lane) * 8);
          #pragma unroll
          for (int mt = 0; mt < 2; ++mt) {
            f32x4 c = (kt == 0) ? bb[2 * p + ntl].v : acc[ntl][mt];
            acc[ntl][mt] = __builtin_amdgcn_mfma_f32_16x16x32_bf16(wf.v, hin[mt][kt].v, c, 0, 0, 0);
          }
        }
      #pragma unroll
      for (int mt = 0; mt < 2; ++mt)
        #pragma unroll
        for (int ntl = 0; ntl < 2; ++ntl) {
          f32x4 r = __builtin_elementwise_max(acc[ntl][mt], zero4);
          uint32_t xw0 = x0f[mt][p].u[2 * ntl + 0];
          uint32_t xw1 = x0f[mt][p].u[2 * ntl + 1];
          f32x4 xv;
          xv[0] = __uint_as_float(xw0 << 16);
          xv[1] = __uint_as_float(xw0 & 0xffff0000u);
          xv[2] = __uint_as_float(xw1 << 16);
          xv[3] = __uint_as_float(xw1 & 0xffff0000u);
          r = r + xv;
          hout[mt][p].u[2 * ntl + 0] = cvtpk(r[0], r[1]);
          hout[mt][p].u[2 * ntl + 1] = cvtpk(r[2], r[3]);
        }
    }
  };

  // ---- start layer (pipelined over its 2 chunks) ----
  F4 barr[8];
  #pragma unroll
  for (int nt = 0; nt < 8; ++nt)
    barr[nt].f = *reinterpret_cast<const float4*>(b_start + nt * 16 + q * 4);

  __syncthreads();                           // X = Wsc0 ready
  stage(Y, wfrag + 8192);                    // Wsc1
  start_half(X, 0, barr);
  __syncthreads();                           // Y ready, X reads done
  const uint16_t* chain = wfrag + 16384;
  stage(X, chain);                           // L0c0
  start_half(Y, 2, barr);
  #pragma unroll
  for (int mt = 0; mt < 2; ++mt)
    #pragma unroll
    for (int kt = 0; kt < 4; ++kt)
      hA[mt][kt].v = x0f[mt][kt].v;          // h = x0

  // ---- 32 layers, 2 chunks each; h ping-pong via 2x unroll ----
  #pragma unroll 1
  for (int l = 0; l < 32; l += 2) {
    // layer l: hA -> hB
    __syncthreads();                         // X = Ll c0 ready
    stage(Y, chain + l * 16384 + 8192);      // Ll c1
    {
      const float* bl = layer_b + l * 128;
      #pragma unroll
      for (int nt = 0; nt < 8; ++nt)
        barr[nt].f = *reinterpret_cast<const float4*>(bl + nt * 16 + q * 4);
    }
    chain_half(X, 0, barr, hA, hB);
    __syncthreads();                         // Y ready, X reads done
    stage(X, chain + (l + 1) * 16384);       // L(l+1) c0
    chain_half(Y, 2, barr, hA, hB);

    // layer l+1: hB -> hA
    __syncthreads();                         // X = L(l+1) c0 ready
    stage(Y, chain + (l + 1) * 16384 + 8192);// L(l+1) c1
    {
      const float* bl = layer_b + (l + 1) * 128;
      #pragma unroll
      for (int nt = 0; nt < 8; ++nt)
        barr[nt].f = *reinterpret_cast<const float4*>(bl + nt * 16 + q * 4);
    }
    chain_half(X, 0, barr, hB, hA);
    __syncthreads();                         // Y ready, X reads done
    if (l + 2 < 32) stage(X, chain + (l + 2) * 16384);
    chain_half(Y, 2, barr, hB, hA);
  }
  __syncthreads();                           // all chain compute done; LDS free

  // ---- output layer: logits^T = Wo * h^T + bo (W_out from global, L2) ----
  const uint16_t* wout = wfrag + 540672;
  F4 bo[4];
  #pragma unroll
  for (int nt = 0; nt < 4; ++nt)
    bo[nt].f = *reinterpret_cast<const float4*>(b_out + nt * 16 + q * 4);
  f32x4 ao[4][2];  // [nt][mt]
  #pragma unroll
  for (int kt = 0; kt < 4; ++kt) {
    #pragma unroll
    for (int nt = 0; nt < 4; ++nt) {
      Frag wf;
      wf.v = *reinterpret_cast<const bs8*>(wout + ((nt * 4 + kt) * 64 + lane) * 8);
      #pragma unroll
      for (int mt = 0; mt < 2; ++mt) {
        f32x4 c = (kt == 0) ? bo[nt].v : ao[nt][mt];
        ao[nt][mt] = __builtin_amdgcn_mfma_f32_16x16x32_bf16(wf.v, hA[mt][kt].v, c, 0, 0, 0);
      }
    }
  }

  // ---- softmax over 64 classes + transposed store via LDS scratch ----
  float* tr = reinterpret_cast<float*>(lds) + wave * 1088;   // 16x68 floats
  #pragma unroll
  for (int mt = 0; mt < 2; ++mt) {
    float e[16];
    float M = -3.0e38f;
    #pragma unroll
    for (int nt = 0; nt < 4; ++nt)
      #pragma unroll
      for (int r = 0; r < 4; ++r)
        M = fmaxf(M, ao[nt][mt][r]);
    M = fmaxf(M, __shfl_xor(M, 16, 64));
    M = fmaxf(M, __shfl_xor(M, 32, 64));
    float S = 0.0f;
    #pragma unroll
    for (int nt = 0; nt < 4; ++nt)
      #pragma unroll
      for (int r = 0; r < 4; ++r) {
        float t = exp2f((ao[nt][mt][r] - M) * 1.4426950408889634f);
        e[nt * 4 + r] = t;
        S += t;
      }
    S += __shfl_xor(S, 16, 64);
    S += __shfl_xor(S, 32, 64);
    const float inv = 1.0f / S;
    #pragma unroll
    for (int nt = 0; nt < 4; ++nt) {
      float4 pv;
      pv.x = e[nt * 4 + 0] * inv;
      pv.y = e[nt * 4 + 1] * inv;
      pv.z = e[nt * 4 + 2] * inv;
      pv.w = e[nt * 4 + 3] * inv;
      *reinterpret_cast<float4*>(tr + mc * 68 + nt * 16 + q * 4) = pv;
    }
    __asm__ volatile("s_waitcnt lgkmcnt(0)" ::: "memory");
    #pragma unroll
    for (int it = 0; it < 4; ++it) {
      int row = it * 4 + (lane >> 4);
      float4 v = *reinterpret_cast<const float4*>(tr + row * 68 + (lane & 15) * 4);
      long gr = batch0 + mt * 16 + row;
      *reinterpret_cast<float4*>(out + gr * 64 + (lane & 15) * 4) = v;
    }
    __asm__ volatile("s_waitcnt lgkmcnt(0)" ::: "memory");
  }
}

// ---------------------------------------------------------------------------
extern "C" void kernel_launch(void* const* d_in, const int* in_sizes, int n_in,
                              void* d_out, int out_size, void* d_ws, size_t ws_size,
                              hipStream_t stream) {
  const float* x        = (const float*)d_in[0];
  const float* w_start  = (const float*)d_in[1];
  const float* b_start  = (const float*)d_in[2];
  const float* masked_w = (const float*)d_in[3];
  const float* layer_b  = (const float*)d_in[4];
  const float* w_out    = (const float*)d_in[5];
  const float* b_out    = (const float*)d_in[6];
  uint16_t* wfrag = (uint16_t*)d_ws;   // 1,097,728 B < ws_size

  prep_frags<<<268, 256, 0, stream>>>(w_start, masked_w, w_out, wfrag);
  wann_main<<<1024, 256, 32768, stream>>>(x, b_start, layer_b, b_out, wfrag,
                                          (float*)d_out);
}

// Round 2
// 322.092 us; speedup vs baseline: 1.3125x; 1.3125x over previous
//
#include <hip/hip_runtime.h>
#include <hip/hip_bf16.h>
#include <stdint.h>

// ---------------------------------------------------------------------------
// wannModel: x0 = x@Ws^T + bs;  h_{l+1} = relu(h_l@W_l^T + b_l) + x0 (32x);
//            out = softmax(h@Wo^T + bo)  over 64 classes.
//
// Transposed-orientation MFMA chain (out^T = W * h^T). k-index mismatch
// absorbed by pre-permuting weights' k axis (pi) in a prep kernel. h stays
// in registers across all 32 layers.
//
// R7 post-mortem: launch_bounds(256,4) => joint (arch+acc) budget 128 <
// ~168 demand -> spills (FETCH 44->375MB). 4 blocks/CU at mt=2 impossible.
// R8: the LDS weight stream is PER-WAVE (every wave reads all 32KB/layer),
// so halve it by doubling rows/wave: mt=4 (64 rows/wave), 512 blocks,
// launch_bounds(256,2) -> joint budget 256 vs ~235 demand; grid == exactly
// 2 blocks/CU (no tail). Biases staged to LDS once (17KB) to kill the
// 32-reg per-layer barr[] file; acc zero-init, bias added in epilogue
// (per-pass bias ds_read hides under 16 MFMAs). MFMA pipe (~166k cy/CU)
// becomes the binding resource; LDS stream drops to ~99k cy/CU.
// ---------------------------------------------------------------------------

typedef short bs8 __attribute__((ext_vector_type(8)));   // 8 x bf16 bits
typedef float f32x4 __attribute__((ext_vector_type(4)));

union Frag { bs8 v; uint32_t u[4]; };
union F4   { float4 f; f32x4 v; };

__device__ __forceinline__ uint32_t cvtpk(float lo, float hi) {
#if __has_builtin(__builtin_amdgcn_cvt_pk_bf16_f32)
  auto r = __builtin_amdgcn_cvt_pk_bf16_f32(lo, hi);   // dst.lo=cvt(lo)
  uint32_t u; __builtin_memcpy(&u, &r, 4);
  return u;
#else
  union { float f; uint32_t u; } a, b; a.f = lo; b.f = hi;
  uint32_t ra = a.u + 0x7fffu + ((a.u >> 16) & 1u);    // RNE, no NaN check
  uint32_t rb = b.u + 0x7fffu + ((b.u >> 16) & 1u);
  return (ra >> 16) | (rb & 0xffff0000u);
#endif
}

// ---------------------------------------------------------------------------
// Preprocess: bf16 weight fragments in d_ws. uint16 layout:
//   [0,16384)       W_start frags, NATURAL k order
//   [16384,540672)  32 chain layers, PI-permuted k
//   [540672,548864) W_out frags, PI-permuted k
// Element offset in region: ((nt*4+kt)*64 + lane)*8 + j.
// Half-layer chunk c of a layer = nt in [4c,4c+4) = 8192 contiguous elements.
// ---------------------------------------------------------------------------
__global__ void prep_frags(const float* __restrict__ w_start,
                           const float* __restrict__ masked_w,
                           const float* __restrict__ w_out,
                           uint16_t* __restrict__ dst) {
  int t = blockIdx.x * 256 + threadIdx.x;
  if (t >= 68608) return;
  int lane = t & 63, kt = (t >> 6) & 3, q = lane >> 4, m15 = lane & 15;
  float f[8];
  if (t < 2048) {                              // W_start (natural k)
    int nt = (t >> 8) & 7;
    const float* s = w_start + (nt * 16 + m15) * 128 + q * 8 + kt * 32;
    #pragma unroll
    for (int j = 0; j < 8; ++j) f[j] = s[j];
  } else if (t < 67584) {                      // chain (pi-permuted k)
    int t2 = t - 2048, l = t2 >> 11, nt = (t2 >> 8) & 7;
    const float* s = masked_w + ((l * 128) + nt * 16 + m15) * 128 + q * 4 + kt * 32;
    #pragma unroll
    for (int j = 0; j < 8; ++j) f[j] = s[(j & 3) + 16 * (j >> 2)];
  } else {                                     // W_out (pi-permuted k)
    int t3 = t - 67584, nt = (t3 >> 8) & 3;
    const float* s = w_out + (nt * 16 + m15) * 128 + q * 4 + kt * 32;
    #pragma unroll
    for (int j = 0; j < 8; ++j) f[j] = s[(j & 3) + 16 * (j >> 2)];
  }
  uint4 o;
  o.x = cvtpk(f[0], f[1]); o.y = cvtpk(f[2], f[3]);
  o.z = cvtpk(f[4], f[5]); o.w = cvtpk(f[6], f[7]);
  *reinterpret_cast<uint4*>(dst + t * 8) = o;
}

// ---------------------------------------------------------------------------
// Main kernel: 512 blocks x 256 threads (4 waves; wave owns 64 batch cols
// = 4 m-tiles of 16). LDS 49920B: X|Y 16KB half-layer chunk double-buffer
// + 17152B bias table (b_start | 32 x layer_b | b_out as floats).
// Chunk stream: Wsc0, Wsc1, L0c0, L0c1, ..., L31c1; even chunks -> X,
// odd -> Y. Passes 0,1 of every layer read X; passes 2,3 read Y.
// Exactly 2 blocks/CU resident; grid == one dispatch wave, no tail.
// ---------------------------------------------------------------------------
extern __shared__ uint16_t lds[];

__global__ void __launch_bounds__(256, 2)
wann_main(const float* __restrict__ x,
          const float* __restrict__ b_start,
          const float* __restrict__ layer_b,
          const float* __restrict__ b_out,
          const uint16_t* __restrict__ wfrag,
          float* __restrict__ out) {
  const int tid  = threadIdx.x;
  const int lane = tid & 63;
  const int wave = tid >> 6;
  const int q    = lane >> 4;
  const int mc   = lane & 15;
  const long batch0 = (long)blockIdx.x * 256 + wave * 64;
  const f32x4 zero4 = {0.f, 0.f, 0.f, 0.f};

  uint16_t* X = lds;
  uint16_t* Y = lds + 8192;
  float* bsh = reinterpret_cast<float*>(lds + 16384);  // bias table (floats)
  // bsh[0..127]=b_start; bsh[128+l*128+n]=layer_b[l][n]; bsh[4224..4287]=b_out

  // stage one 16KB chunk (4 x width-16 global_load_lds per wave)
  auto stage = [&](uint16_t* dstb, const uint16_t* srcb) {
    #pragma unroll
    for (int i = 0; i < 4; ++i) {
      __builtin_amdgcn_global_load_lds(
          (const __attribute__((address_space(1))) void*)(srcb + i * 2048 + wave * 512 + lane * 8),
          (__attribute__((address_space(3))) void*)(dstb + i * 2048 + wave * 512),
          16, 0, 0);
    }
  };

  stage(X, wfrag);                           // W_start chunk0

  // ---- stage biases into LDS (once) ----
  {
    float4* d = reinterpret_cast<float4*>(bsh);
    if (tid < 32) d[tid] = reinterpret_cast<const float4*>(b_start)[tid];
    #pragma unroll
    for (int r = 0; r < 4; ++r) {
      int i = tid + r * 256;                 // 0..1023 float4s of layer_b
      reinterpret_cast<float4*>(bsh + 128)[i] =
          reinterpret_cast<const float4*>(layer_b)[i];
    }
    if (tid < 16)
      reinterpret_cast<float4*>(bsh + 4224)[tid] =
          reinterpret_cast<const float4*>(b_out)[tid];
  }

  // ---- load x fragments (natural k: B[k=8q+j+32kt][batch=mc]) ----
  Frag xf[4][4];
  #pragma unroll
  for (int mt = 0; mt < 4; ++mt) {
    const float* xrow = x + (batch0 + mt * 16 + mc) * 128 + q * 8;
    #pragma unroll
    for (int kt = 0; kt < 4; ++kt) {
      float4 a = *reinterpret_cast<const float4*>(xrow + kt * 32);
      float4 b = *reinterpret_cast<const float4*>(xrow + kt * 32 + 4);
      xf[mt][kt].u[0] = cvtpk(a.x, a.y);
      xf[mt][kt].u[1] = cvtpk(a.z, a.w);
      xf[mt][kt].u[2] = cvtpk(b.x, b.y);
      xf[mt][kt].u[3] = cvtpk(b.z, b.w);
    }
  }

  Frag x0f[4][4], hA[4][4], hB[4][4];

  // ---- start layer half: 2 passes from `buf`; x0f = acc + bias ----
  auto start_half = [&](const uint16_t* buf, int p0) {
    #pragma unroll
    for (int pp = 0; pp < 2; ++pp) {
      const int p = p0 + pp;
      #pragma unroll
      for (int ntl = 0; ntl < 2; ++ntl) {
        const int ntloc = 2 * pp + ntl;           // nt within chunk
        F4 bb;
        bb.f = *reinterpret_cast<const float4*>(bsh + (2 * p + ntl) * 16 + q * 4);
        f32x4 acc[4];
        #pragma unroll
        for (int mt = 0; mt < 4; ++mt) acc[mt] = zero4;
        #pragma unroll
        for (int kt = 0; kt < 4; ++kt) {
          Frag wf;
          wf.v = *reinterpret_cast<const bs8*>(buf + ((ntloc * 4 + kt) * 64 + lane) * 8);
          #pragma unroll
          for (int mt = 0; mt < 4; ++mt)
            acc[mt] = __builtin_amdgcn_mfma_f32_16x16x32_bf16(wf.v, xf[mt][kt].v, acc[mt], 0, 0, 0);
        }
        #pragma unroll
        for (int mt = 0; mt < 4; ++mt) {
          f32x4 r = acc[mt] + bb.v;
          x0f[mt][p].u[2 * ntl + 0] = cvtpk(r[0], r[1]);
          x0f[mt][p].u[2 * ntl + 1] = cvtpk(r[2], r[3]);
        }
      }
    }
  };

  // ---- chain layer half: hout = bf16(relu(acc + b) + x0) ----
  auto chain_half = [&](const uint16_t* buf, int p0, const float* bptr,
                        Frag (&hin)[4][4], Frag (&hout)[4][4]) {
    #pragma unroll
    for (int pp = 0; pp < 2; ++pp) {
      const int p = p0 + pp;
      #pragma unroll
      for (int ntl = 0; ntl < 2; ++ntl) {
        const int ntloc = 2 * pp + ntl;
        F4 bb;
        bb.f = *reinterpret_cast<const float4*>(bptr + (2 * p + ntl) * 16 + q * 4);
        f32x4 acc[4];
        #pragma unroll
        for (int mt = 0; mt < 4; ++mt) acc[mt] = zero4;
        #pragma unroll
        for (int kt = 0; kt < 4; ++kt) {
          Frag wf;
          wf.v = *reinterpret_cast<const bs8*>(buf + ((ntloc * 4 + kt) * 64 + lane) * 8);
          #pragma unroll
          for (int mt = 0; mt < 4; ++mt)
            acc[mt] = __builtin_amdgcn_mfma_f32_16x16x32_bf16(wf.v, hin[mt][kt].v, acc[mt], 0, 0, 0);
        }
        #pragma unroll
        for (int mt = 0; mt < 4; ++mt) {
          f32x4 r = __builtin_elementwise_max(acc[mt] + bb.v, zero4);
          uint32_t xw0 = x0f[mt][p].u[2 * ntl + 0];
          uint32_t xw1 = x0f[mt][p].u[2 * ntl + 1];
          f32x4 xv;
          xv[0] = __uint_as_float(xw0 << 16);
          xv[1] = __uint_as_float(xw0 & 0xffff0000u);
          xv[2] = __uint_as_float(xw1 << 16);
          xv[3] = __uint_as_float(xw1 & 0xffff0000u);
          r = r + xv;
          hout[mt][p].u[2 * ntl + 0] = cvtpk(r[0], r[1]);
          hout[mt][p].u[2 * ntl + 1] = cvtpk(r[2], r[3]);
        }
      }
    }
  };

  // ---- start layer (pipelined over its 2 chunks) ----
  __syncthreads();                           // X = Wsc0 ready, biases ready
  stage(Y, wfrag + 8192);                    // Wsc1
  start_half(X, 0);
  __syncthreads();                           // Y ready, X reads done
  const uint16_t* chain = wfrag + 16384;
  stage(X, chain);                           // L0c0
  start_half(Y, 2);
  #pragma unroll
  for (int mt = 0; mt < 4; ++mt)
    #pragma unroll
    for (int kt = 0; kt < 4; ++kt)
      hA[mt][kt].v = x0f[mt][kt].v;          // h = x0

  // ---- 32 layers, 2 chunks each; h ping-pong via 2x unroll ----
  #pragma unroll 1
  for (int l = 0; l < 32; l += 2) {
    // layer l: hA -> hB
    const float* bl0 = bsh + 128 + l * 128;
    const float* bl1 = bsh + 128 + (l + 1) * 128;
    __syncthreads();                         // X = Ll c0 ready
    stage(Y, chain + l * 16384 + 8192);      // Ll c1
    chain_half(X, 0, bl0, hA, hB);
    __syncthreads();                         // Y ready, X reads done
    stage(X, chain + (l + 1) * 16384);       // L(l+1) c0
    chain_half(Y, 2, bl0, hA, hB);

    // layer l+1: hB -> hA
    __syncthreads();                         // X = L(l+1) c0 ready
    stage(Y, chain + (l + 1) * 16384 + 8192);// L(l+1) c1
    chain_half(X, 0, bl1, hB, hA);
    __syncthreads();                         // Y ready, X reads done
    if (l + 2 < 32) stage(X, chain + (l + 2) * 16384);
    chain_half(Y, 2, bl1, hB, hA);
  }
  __syncthreads();                           // all chain compute done

  // ---- output layer: logits^T = Wo * h^T + bo (W_out from global, L2) ----
  const uint16_t* wout = wfrag + 540672;
  F4 bo[4];
  #pragma unroll
  for (int nt = 0; nt < 4; ++nt)
    bo[nt].f = *reinterpret_cast<const float4*>(bsh + 4224 + nt * 16 + q * 4);
  f32x4 ao[4][4];  // [nt][mt]
  #pragma unroll
  for (int kt = 0; kt < 4; ++kt) {
    #pragma unroll
    for (int nt = 0; nt < 4; ++nt) {
      Frag wf;
      wf.v = *reinterpret_cast<const bs8*>(wout + ((nt * 4 + kt) * 64 + lane) * 8);
      #pragma unroll
      for (int mt = 0; mt < 4; ++mt) {
        f32x4 c = (kt == 0) ? bo[nt].v : ao[nt][mt];
        ao[nt][mt] = __builtin_amdgcn_mfma_f32_16x16x32_bf16(wf.v, hA[mt][kt].v, c, 0, 0, 0);
      }
    }
  }

  // ---- softmax over 64 classes + transposed store via LDS scratch ----
  float* tr = reinterpret_cast<float*>(lds) + wave * 1088;   // 16x68 floats
  #pragma unroll
  for (int mt = 0; mt < 4; ++mt) {
    float e[16];
    float M = -3.0e38f;
    #pragma unroll
    for (int nt = 0; nt < 4; ++nt)
      #pragma unroll
      for (int r = 0; r < 4; ++r)
        M = fmaxf(M, ao[nt][mt][r]);
    M = fmaxf(M, __shfl_xor(M, 16, 64));
    M = fmaxf(M, __shfl_xor(M, 32, 64));
    float S = 0.0f;
    #pragma unroll
    for (int nt = 0; nt < 4; ++nt)
      #pragma unroll
      for (int r = 0; r < 4; ++r) {
        float t = exp2f((ao[nt][mt][r] - M) * 1.4426950408889634f);
        e[nt * 4 + r] = t;
        S += t;
      }
    S += __shfl_xor(S, 16, 64);
    S += __shfl_xor(S, 32, 64);
    const float inv = 1.0f / S;
    #pragma unroll
    for (int nt = 0; nt < 4; ++nt) {
      float4 pv;
      pv.x = e[nt * 4 + 0] * inv;
      pv.y = e[nt * 4 + 1] * inv;
      pv.z = e[nt * 4 + 2] * inv;
      pv.w = e[nt * 4 + 3] * inv;
      *reinterpret_cast<float4*>(tr + mc * 68 + nt * 16 + q * 4) = pv;
    }
    __asm__ volatile("s_waitcnt lgkmcnt(0)" ::: "memory");
    #pragma unroll
    for (int it = 0; it < 4; ++it) {
      int row = it * 4 + (lane >> 4);
      float4 v = *reinterpret_cast<const float4*>(tr + row * 68 + (lane & 15) * 4);
      long gr = batch0 + mt * 16 + row;
      *reinterpret_cast<float4*>(out + gr * 64 + (lane & 15) * 4) = v;
    }
    __asm__ volatile("s_waitcnt lgkmcnt(0)" ::: "memory");
  }
}

// ---------------------------------------------------------------------------
extern "C" void kernel_launch(void* const* d_in, const int* in_sizes, int n_in,
                              void* d_out, int out_size, void* d_ws, size_t ws_size,
                              hipStream_t stream) {
  const float* x        = (const float*)d_in[0];
  const float* w_start  = (const float*)d_in[1];
  const float* b_start  = (const float*)d_in[2];
  const float* masked_w = (const float*)d_in[3];
  const float* layer_b  = (const float*)d_in[4];
  const float* w_out    = (const float*)d_in[5];
  const float* b_out    = (const float*)d_in[6];
  uint16_t* wfrag = (uint16_t*)d_ws;   // 1,097,728 B < ws_size

  prep_frags<<<268, 256, 0, stream>>>(w_start, masked_w, w_out, wfrag);
  wann_main<<<512, 256, 49920, stream>>>(x, b_start, layer_b, b_out, wfrag,
                                         (float*)d_out);
}

// Round 3
// 270.220 us; speedup vs baseline: 1.5645x; 1.1920x over previous
//
#include <hip/hip_runtime.h>
#include <hip/hip_bf16.h>
#include <stdint.h>

// ---------------------------------------------------------------------------
// wannModel: x0 = x@Ws^T + bs;  h_{l+1} = relu(h_l@W_l^T + b_l) + x0 (32x);
//            out = softmax(h@Wo^T + bo)  over 64 classes.
//
// Transposed-orientation MFMA chain (out^T = W * h^T). k-index mismatch
// absorbed by pre-permuting weights' k axis (pi) in a prep kernel. h stays
// in registers across all 32 layers (mt=2: 32 rows/wave, 12 waves/CU).
//
// R8 post-mortem: mt=4 @ 2 blocks/CU spilled (WRITE +14MB) and starved the
// MFMA pipe (MfmaUtil 23.7%). R6 (mt=2, 3 blocks/CU) stays the base.
// R9: R6's pipes (LDS 199k + MFMA 166k + VALU 107k cy/CU) SUM to the
// measured 533k -> serialized by 132 draining __syncthreads (vmcnt(0) at
// every barrier). Fix = T3/T4: triple-buffered 16.25KB chunks, ONE raw
// s_barrier per chunk (66 total), counted `s_waitcnt vmcnt(5)` so the
// 2-ahead prefetch stays in flight across barriers. Biases are baked into
// the chunk stream (16KB weights + 256B bias half-layer) so stage = exactly
// 5 global_load_lds/wave and nothing else touches vmcnt. W_out+b_out =
// chunk 66 (LDS). T5 setprio(1) around MFMA clusters.
// ---------------------------------------------------------------------------

typedef short bs8 __attribute__((ext_vector_type(8)));   // 8 x bf16 bits
typedef float f32x4 __attribute__((ext_vector_type(4)));

union Frag { bs8 v; uint32_t u[4]; };
union F4   { float4 f; f32x4 v; };

__device__ __forceinline__ uint32_t cvtpk(float lo, float hi) {
#if __has_builtin(__builtin_amdgcn_cvt_pk_bf16_f32)
  auto r = __builtin_amdgcn_cvt_pk_bf16_f32(lo, hi);   // dst.lo=cvt(lo)
  uint32_t u; __builtin_memcpy(&u, &r, 4);
  return u;
#else
  union { float f; uint32_t u; } a, b; a.f = lo; b.f = hi;
  uint32_t ra = a.u + 0x7fffu + ((a.u >> 16) & 1u);    // RNE, no NaN check
  uint32_t rb = b.u + 0x7fffu + ((b.u >> 16) & 1u);
  return (ra >> 16) | (rb & 0xffff0000u);
#endif
}

// ---------------------------------------------------------------------------
// Preprocess. Chunk layout in d_ws (uint16 units, 8320 elems = 16640 B each):
//   chunk c base = c*8320.  [0,8192) = weight frags (4 ntloc x 4 kt),
//   [8192,8320) = 256 B bias (64 floats for this half-layer).
// Chunks: 0,1 = W_start halves (NATURAL k) + b_start halves;
//         2+2l+h = layer l half h (PI-permuted k) + layer_b[l] half h;
//         66 = W_out (4 nt, PI-permuted) + b_out (64 floats).
// Weight element in chunk: ((ntloc*4+kt)*64 + lane)*8 + j.
// ---------------------------------------------------------------------------
__global__ void prep_frags(const float* __restrict__ w_start,
                           const float* __restrict__ b_start,
                           const float* __restrict__ masked_w,
                           const float* __restrict__ layer_b,
                           const float* __restrict__ w_out,
                           const float* __restrict__ b_out,
                           uint16_t* __restrict__ dst) {
  int t = blockIdx.x * 256 + threadIdx.x;
  if (t >= 69680) return;
  if (t >= 68608) {                            // bias floats, 4 per thread
    int f = (t - 68608) * 4;
    int c, off; const float* src;
    if (f < 128)       { c = f >> 6;               off = f & 63; src = b_start + f; }
    else if (f < 4224) { int g = f - 128;  c = 2 + (g >> 6); off = g & 63; src = layer_b + g; }
    else               { int g = f - 4224; c = 66;           off = g;      src = b_out + g; }
    float4 v = *reinterpret_cast<const float4*>(src);
    *reinterpret_cast<float4*>(
        reinterpret_cast<float*>(dst + (size_t)c * 8320 + 8192) + off) = v;
    return;
  }
  int lane = t & 63, kt = (t >> 6) & 3, q = lane >> 4, m15 = lane & 15;
  float f[8];
  int c, ntloc;
  if (t < 2048) {                              // W_start (natural k)
    int nt = (t >> 8) & 7;
    c = nt >> 2; ntloc = nt & 3;
    const float* s = w_start + (nt * 16 + m15) * 128 + q * 8 + kt * 32;
    #pragma unroll
    for (int j = 0; j < 8; ++j) f[j] = s[j];
  } else if (t < 67584) {                      // chain (pi-permuted k)
    int t2 = t - 2048, l = t2 >> 11, nt = (t2 >> 8) & 7;
    c = 2 + 2 * l + (nt >> 2); ntloc = nt & 3;
    const float* s = masked_w + ((l * 128) + nt * 16 + m15) * 128 + q * 4 + kt * 32;
    #pragma unroll
    for (int j = 0; j < 8; ++j) f[j] = s[(j & 3) + 16 * (j >> 2)];
  } else {                                     // W_out (pi-permuted k)
    int t3 = t - 67584, nt = (t3 >> 8) & 3;
    c = 66; ntloc = nt;
    const float* s = w_out + (nt * 16 + m15) * 128 + q * 4 + kt * 32;
    #pragma unroll
    for (int j = 0; j < 8; ++j) f[j] = s[(j & 3) + 16 * (j >> 2)];
  }
  uint4 o;
  o.x = cvtpk(f[0], f[1]); o.y = cvtpk(f[2], f[3]);
  o.z = cvtpk(f[4], f[5]); o.w = cvtpk(f[6], f[7]);
  *reinterpret_cast<uint4*>(dst + (size_t)c * 8320 +
                            ((ntloc * 4 + kt) * 64 + lane) * 8) = o;
}

// ---------------------------------------------------------------------------
// Main kernel: 1024 blocks x 256 threads (4 waves; wave owns 32 batch cols
// = 2 m-tiles of 16). LDS 49920B = 3 chunk slots of 8320 uint16.
// Phase(c): s_waitcnt vmcnt(5) -> s_barrier -> stage chunk c+2 -> compute c.
// Loads for c+1 and c+2 stay in flight across the barrier (T3/T4).
// 3 blocks/CU resident; independent blocks cover each other's phases.
// ---------------------------------------------------------------------------
extern __shared__ uint16_t lds[];

#define VMW(N) asm volatile("s_waitcnt vmcnt(" #N ")" ::: "memory")

__global__ void __launch_bounds__(256, 3)
wann_main(const float* __restrict__ x,
          const uint16_t* __restrict__ wfrag,
          float* __restrict__ out) {
  const int tid  = threadIdx.x;
  const int lane = tid & 63;
  const int wave = tid >> 6;
  const int q    = lane >> 4;
  const int mc   = lane & 15;
  const long batch0 = (long)blockIdx.x * 128 + wave * 32;
  const f32x4 zero4 = {0.f, 0.f, 0.f, 0.f};

  auto slotp = [&](uint32_t s) -> uint16_t* { return lds + (size_t)s * 8320; };

  // stage one chunk: 4 x width-16 (weights) + 1 x width-4 (bias) per wave.
  // Exactly 5 vmcnt ops per stage -> counted waits are exact.
  auto stage = [&](uint16_t* dstb, uint32_t c) {
    const uint16_t* srcb = wfrag + (size_t)c * 8320;
    #pragma unroll
    for (int i = 0; i < 4; ++i) {
      __builtin_amdgcn_global_load_lds(
          (const __attribute__((address_space(1))) void*)(srcb + i * 2048 + wave * 512 + lane * 8),
          (__attribute__((address_space(3))) void*)(dstb + i * 2048 + wave * 512),
          16, 0, 0);
    }
    // bias: all 4 waves write the same 256B (same data; benign duplication)
    __builtin_amdgcn_global_load_lds(
        (const __attribute__((address_space(1))) void*)(srcb + 8192 + lane * 2),
        (__attribute__((address_space(3))) void*)(dstb + 8192),
        4, 0, 0);
  };

  auto barx = [&]() {
    asm volatile("" ::: "memory");
    __builtin_amdgcn_s_barrier();
    asm volatile("" ::: "memory");
  };

  // ---- load x fragments (natural k: B[k=8q+j+32kt][batch=mc]) ----
  Frag xf[2][4];
  #pragma unroll
  for (int mt = 0; mt < 2; ++mt) {
    const float* xrow = x + (batch0 + mt * 16 + mc) * 128 + q * 8;
    #pragma unroll
    for (int kt = 0; kt < 4; ++kt) {
      float4 a = *reinterpret_cast<const float4*>(xrow + kt * 32);
      float4 b = *reinterpret_cast<const float4*>(xrow + kt * 32 + 4);
      xf[mt][kt].u[0] = cvtpk(a.x, a.y);
      xf[mt][kt].u[1] = cvtpk(a.z, a.w);
      xf[mt][kt].u[2] = cvtpk(b.x, b.y);
      xf[mt][kt].u[3] = cvtpk(b.z, b.w);
    }
  }

  stage(slotp(0), 0);                        // W_start half 0
  stage(slotp(1), 1);                        // W_start half 1

  Frag x0f[2][4], hA[2][4], hB[2][4];

  // ---- start layer half h: 2 passes; acc init = bias (from chunk LDS) ----
  auto start_half = [&](const uint16_t* buf, int h) {
    const float* bbb = reinterpret_cast<const float*>(buf + 8192);
    #pragma unroll
    for (int pp = 0; pp < 2; ++pp) {
      const int p = 2 * h + pp;
      F4 bb[2];
      #pragma unroll
      for (int ntl = 0; ntl < 2; ++ntl)
        bb[ntl].f = *reinterpret_cast<const float4*>(bbb + (2 * pp + ntl) * 16 + q * 4);
      f32x4 acc[2][2];
      __builtin_amdgcn_s_setprio(1);
      #pragma unroll
      for (int kt = 0; kt < 4; ++kt)
        #pragma unroll
        for (int ntl = 0; ntl < 2; ++ntl) {
          const int ntloc = 2 * pp + ntl;
          Frag wf;
          wf.v = *reinterpret_cast<const bs8*>(buf + ((ntloc * 4 + kt) * 64 + lane) * 8);
          #pragma unroll
          for (int mt = 0; mt < 2; ++mt) {
            f32x4 c = (kt == 0) ? bb[ntl].v : acc[ntl][mt];
            acc[ntl][mt] = __builtin_amdgcn_mfma_f32_16x16x32_bf16(wf.v, xf[mt][kt].v, c, 0, 0, 0);
          }
        }
      __builtin_amdgcn_s_setprio(0);
      #pragma unroll
      for (int mt = 0; mt < 2; ++mt)
        #pragma unroll
        for (int ntl = 0; ntl < 2; ++ntl) {
          x0f[mt][p].u[2 * ntl + 0] = cvtpk(acc[ntl][mt][0], acc[ntl][mt][1]);
          x0f[mt][p].u[2 * ntl + 1] = cvtpk(acc[ntl][mt][2], acc[ntl][mt][3]);
        }
    }
  };

  // ---- chain layer half h: hout = bf16(relu(acc_with_bias) + x0) ----
  auto chain_half = [&](const uint16_t* buf, int h,
                        Frag (&hin)[2][4], Frag (&hout)[2][4]) {
    const float* bbb = reinterpret_cast<const float*>(buf + 8192);
    #pragma unroll
    for (int pp = 0; pp < 2; ++pp) {
      const int p = 2 * h + pp;
      F4 bb[2];
      #pragma unroll
      for (int ntl = 0; ntl < 2; ++ntl)
        bb[ntl].f = *reinterpret_cast<const float4*>(bbb + (2 * pp + ntl) * 16 + q * 4);
      f32x4 acc[2][2];
      __builtin_amdgcn_s_setprio(1);
      #pragma unroll
      for (int kt = 0; kt < 4; ++kt)
        #pragma unroll
        for (int ntl = 0; ntl < 2; ++ntl) {
          const int ntloc = 2 * pp + ntl;
          Frag wf;
          wf.v = *reinterpret_cast<const bs8*>(buf + ((ntloc * 4 + kt) * 64 + lane) * 8);
          #pragma unroll
          for (int mt = 0; mt < 2; ++mt) {
            f32x4 c = (kt == 0) ? bb[ntl].v : acc[ntl][mt];
            acc[ntl][mt] = __builtin_amdgcn_mfma_f32_16x16x32_bf16(wf.v, hin[mt][kt].v, c, 0, 0, 0);
          }
        }
      __builtin_amdgcn_s_setprio(0);
      #pragma unroll
      for (int mt = 0; mt < 2; ++mt)
        #pragma unroll
        for (int ntl = 0; ntl < 2; ++ntl) {
          f32x4 r = __builtin_elementwise_max(acc[ntl][mt], zero4);
          uint32_t xw0 = x0f[mt][p].u[2 * ntl + 0];
          uint32_t xw1 = x0f[mt][p].u[2 * ntl + 1];
          f32x4 xv;
          xv[0] = __uint_as_float(xw0 << 16);
          xv[1] = __uint_as_float(xw0 & 0xffff0000u);
          xv[2] = __uint_as_float(xw1 << 16);
          xv[3] = __uint_as_float(xw1 & 0xffff0000u);
          r = r + xv;
          hout[mt][p].u[2 * ntl + 0] = cvtpk(r[0], r[1]);
          hout[mt][p].u[2 * ntl + 1] = cvtpk(r[2], r[3]);
        }
    }
  };

  // ---- start layer: phases for chunks 0,1 ----
  VMW(5); barx(); stage(slotp(2), 2);        // L0c0
  start_half(slotp(0), 0);
  VMW(5); barx(); stage(slotp(0), 3);        // L0c1
  start_half(slotp(1), 1);
  #pragma unroll
  for (int mt = 0; mt < 2; ++mt)
    #pragma unroll
    for (int kt = 0; kt < 4; ++kt)
      hA[mt][kt].v = x0f[mt][kt].v;          // h = x0

  // ---- 32 layers, 2 chunks each; slots rotate mod 3; stage 2 ahead ----
  uint32_t s0 = 2;                           // slot of chunk c0 = 2+2l
  #pragma unroll 1
  for (int l = 0; l < 32; l += 2) {
    const uint32_t s1 = (s0 + 1 < 3) ? s0 + 1 : 0;
    const uint32_t s2 = (s1 + 1 < 3) ? s1 + 1 : 0;
    const uint32_t c0 = 2 + 2 * (uint32_t)l;

    // layer l half 0 (chunk c0, slot s0); stage c0+2 -> s2
    VMW(5); barx(); stage(slotp(s2), c0 + 2);
    chain_half(slotp(s0), 0, hA, hB);
    // layer l half 1 (chunk c0+1, slot s1); stage c0+3 -> s0
    VMW(5); barx(); stage(slotp(s0), c0 + 3);
    chain_half(slotp(s1), 1, hA, hB);
    // layer l+1 half 0 (chunk c0+2, slot s2); stage c0+4 -> s1
    VMW(5); barx(); if (c0 + 4 <= 66) stage(slotp(s1), c0 + 4);
    chain_half(slotp(s2), 0, hB, hA);
    // layer l+1 half 1 (chunk c0+3, slot s0); stage c0+5 -> s2
    VMW(5); barx(); if (c0 + 5 <= 66) stage(slotp(s2), c0 + 5);
    chain_half(slotp(s0), 1, hB, hA);

    s0 = s1;
  }

  // ---- output layer: chunk 66 (slot 0): W_out + b_out from LDS ----
  VMW(0); barx();
  const uint16_t* wo = slotp(0);
  const float* bob = reinterpret_cast<const float*>(wo + 8192);
  F4 bo[4];
  #pragma unroll
  for (int nt = 0; nt < 4; ++nt)
    bo[nt].f = *reinterpret_cast<const float4*>(bob + nt * 16 + q * 4);
  f32x4 ao[4][2];  // [nt][mt]
  __builtin_amdgcn_s_setprio(1);
  #pragma unroll
  for (int kt = 0; kt < 4; ++kt) {
    #pragma unroll
    for (int nt = 0; nt < 4; ++nt) {
      Frag wf;
      wf.v = *reinterpret_cast<const bs8*>(wo + ((nt * 4 + kt) * 64 + lane) * 8);
      #pragma unroll
      for (int mt = 0; mt < 2; ++mt) {
        f32x4 c = (kt == 0) ? bo[nt].v : ao[nt][mt];
        ao[nt][mt] = __builtin_amdgcn_mfma_f32_16x16x32_bf16(wf.v, hA[mt][kt].v, c, 0, 0, 0);
      }
    }
  }
  __builtin_amdgcn_s_setprio(0);

  // ---- softmax over 64 classes + transposed store via LDS scratch ----
  // Scratch lives in slots 1..2 (bytes 16640+): slot 0 (W_out) still being
  // read by other waves; slots 1/2 reads all completed before the barrier.
  float* tr = reinterpret_cast<float*>(reinterpret_cast<char*>(lds) + 16640)
              + wave * 1088;                 // 16x68 floats per wave
  #pragma unroll
  for (int mt = 0; mt < 2; ++mt) {
    float e[16];
    float M = -3.0e38f;
    #pragma unroll
    for (int nt = 0; nt < 4; ++nt)
      #pragma unroll
      for (int r = 0; r < 4; ++r)
        M = fmaxf(M, ao[nt][mt][r]);
    M = fmaxf(M, __shfl_xor(M, 16, 64));
    M = fmaxf(M, __shfl_xor(M, 32, 64));
    float S = 0.0f;
    #pragma unroll
    for (int nt = 0; nt < 4; ++nt)
      #pragma unroll
      for (int r = 0; r < 4; ++r) {
        float t = exp2f((ao[nt][mt][r] - M) * 1.4426950408889634f);
        e[nt * 4 + r] = t;
        S += t;
      }
    S += __shfl_xor(S, 16, 64);
    S += __shfl_xor(S, 32, 64);
    const float inv = 1.0f / S;
    #pragma unroll
    for (int nt = 0; nt < 4; ++nt) {
      float4 pv;
      pv.x = e[nt * 4 + 0] * inv;
      pv.y = e[nt * 4 + 1] * inv;
      pv.z = e[nt * 4 + 2] * inv;
      pv.w = e[nt * 4 + 3] * inv;
      *reinterpret_cast<float4*>(tr + mc * 68 + nt * 16 + q * 4) = pv;
    }
    __asm__ volatile("s_waitcnt lgkmcnt(0)" ::: "memory");
    #pragma unroll
    for (int it = 0; it < 4; ++it) {
      int row = it * 4 + (lane >> 4);
      float4 v = *reinterpret_cast<const float4*>(tr + row * 68 + (lane & 15) * 4);
      long gr = batch0 + mt * 16 + row;
      *reinterpret_cast<float4*>(out + gr * 64 + (lane & 15) * 4) = v;
    }
    __asm__ volatile("s_waitcnt lgkmcnt(0)" ::: "memory");
  }
}

// ---------------------------------------------------------------------------
extern "C" void kernel_launch(void* const* d_in, const int* in_sizes, int n_in,
                              void* d_out, int out_size, void* d_ws, size_t ws_size,
                              hipStream_t stream) {
  const float* x        = (const float*)d_in[0];
  const float* w_start  = (const float*)d_in[1];
  const float* b_start  = (const float*)d_in[2];
  const float* masked_w = (const float*)d_in[3];
  const float* layer_b  = (const float*)d_in[4];
  const float* w_out    = (const float*)d_in[5];
  const float* b_out    = (const float*)d_in[6];
  uint16_t* wfrag = (uint16_t*)d_ws;   // 67 chunks x 16640 B = 1,114,880 B

  prep_frags<<<273, 256, 0, stream>>>(w_start, b_start, masked_w, layer_b,
                                      w_out, b_out, wfrag);
  wann_main<<<1024, 256, 49920, stream>>>(x, wfrag, (float*)d_out);
}